// Round 1
// baseline (77.975 us; speedup 1.0000x reference)
//
#include <hip/hip_runtime.h>
#include <math.h>

#define PI_F 3.14159265358979323846f
#define EPS_F 1e-6f

// B=1, V=2, W=32, H=16, M=512, f32 I/O.
//
// One wave (64 lanes) per POINT; 8 waves (512 threads) per block, so one
// LDS light-table build is amortized over 8 points and each thread builds
// exactly one of the 512 entries. All grid angles are odd multiples of
// pi/32, so sincosf is replaced by an 8-entry sin((2k+1)pi/32) table +
// sign/index logic (sin(a+pi/2)=cos a covers the phi axis).
// Each lane handles 8 consecutive light samples (m = lane*8+i, two float4
// vis loads) and computes BOTH views, sharing NdotL / glden / vis /
// L*vis*NdotL across views. LDS tables are stored swizzled
// (sigma(m) = (m&7)*64 + (m>>3)) so reads at i*64+lane are conflict-free.
// Per-sample divides merged into a single v_rcp_f32; h never normalized
// (rsq of |h|^2 folded into the two dot products). BRDF epilogue uses
// Fr*sfac + db*(1-Fr) == Fr*(sfac-db) + db  (3 ops/channel instead of 5).
// Bilinear grid-sample degenerates to exact pixel lookup: Li[m]=env_map[x,y].

__global__ __launch_bounds__(512) void hdr_render_kernel(
    const float* __restrict__ normals,    // (N,3)
    const float* __restrict__ albedo,     // (N,3)
    const float* __restrict__ metallic,   // (N,1)
    const float* __restrict__ smooth,     // (N,1)
    const float* __restrict__ vdirs,      // (N,2,3)
    const float* __restrict__ env_vis,    // (N,512)
    const float* __restrict__ env_map,    // (32,16,3)
    float* __restrict__ out,              // (N,2,3)
    int N)
{
    __shared__ float s_lx[512], s_ly[512], s_lz[512];
    __shared__ float s_L0[512], s_L1[512], s_L2[512];

    const int tid = threadIdx.x;

    // ---- per-light-sample tables (swizzled storage), 1 entry/thread ----
    {
        // sin((2k+1)*pi/32), k = 0..7
        static const float S8[8] = {
            0.09801714f, 0.29028468f, 0.47139674f, 0.63439328f,
            0.77301045f, 0.88192126f, 0.95694034f, 0.99518473f };

        const int m = tid;           // 512 threads == 512 entries
        const int x = m & 31;        // u axis, W=32
        const int y = m >> 5;        // v axis, H=16

        // theta = (2y+1)*pi/32 : st = sin(theta), ct = cos(theta)
        const float st = S8[(y < 8) ? y : (15 - y)];
        float ct = S8[(y < 8) ? (7 - y) : (y - 8)];
        if (y >= 8) ct = -ct;

        // a = (2x+1)*pi/32 ; phi = a + pi/2 -> cos(phi) = -sin(a),
        //                                      sin(phi) =  cos(a)
        const int q = x >> 3, r = x & 7;
        float sin_a = S8[(q & 1) ? (7 - r) : r];
        if (q >= 2) sin_a = -sin_a;
        float cos_a = S8[(q & 1) ? r : (7 - r)];
        if (q == 1 || q == 2) cos_a = -cos_a;

        const float sa = st * ((PI_F / 16.0f) * (2.0f * PI_F / 32.0f));
        const int base = (x * 16 + y) * 3;
        const int sw = (m & 7) * 64 + (m >> 3);   // sigma(m)
        s_lx[sw] = -st * sin_a;                   // sin(theta)*cos(phi)
        s_ly[sw] = ct;
        s_lz[sw] = -st * cos_a;                   // -sin(theta)*sin(phi)
        s_L0[sw] = env_map[base + 0] * sa;
        s_L1[sw] = env_map[base + 1] * sa;
        s_L2[sw] = env_map[base + 2] * sa;
    }
    __syncthreads();

    const int lane = tid & 63;
    const int wave = tid >> 6;                    // 0..7
    const int n = blockIdx.x * 8 + wave;
    if (n >= N) return;

    // ---- per-point scalars ----
    float nx = normals[n * 3 + 0];
    float ny = normals[n * 3 + 1];
    float nz = normals[n * 3 + 2];
    {
        const float inv = 1.0f / fmaxf(sqrtf(nx*nx + ny*ny + nz*nz), 1e-12f);
        nx *= inv; ny *= inv; nz *= inv;
    }
    float vx0 = vdirs[n * 6 + 0], vy0 = vdirs[n * 6 + 1], vz0 = vdirs[n * 6 + 2];
    float vx1 = vdirs[n * 6 + 3], vy1 = vdirs[n * 6 + 4], vz1 = vdirs[n * 6 + 5];
    {
        const float inv = 1.0f / fmaxf(sqrtf(vx0*vx0 + vy0*vy0 + vz0*vz0), 1e-12f);
        vx0 *= inv; vy0 *= inv; vz0 *= inv;
    }
    {
        const float inv = 1.0f / fmaxf(sqrtf(vx1*vx1 + vy1*vy1 + vz1*vz1), 1e-12f);
        vx1 *= inv; vy1 *= inv; vz1 *= inv;
    }
    const float alb0 = albedo[n * 3 + 0];
    const float alb1 = albedo[n * 3 + 1];
    const float alb2 = albedo[n * 3 + 2];
    const float met  = metallic[n];
    const float sm   = smooth[n];

    const float rough  = 1.0f - sm;
    const float alpha  = rough * rough;
    const float alpha2 = alpha * alpha;
    const float a2m1   = alpha2 - 1.0f;
    const float k      = 0.5f * alpha;
    const float omk    = 1.0f - k;
    const float kpe    = k + EPS_F;

    const float NdotV0 = fmaxf(nx*vx0 + ny*vy0 + nz*vz0, EPS_F);
    const float NdotV1 = fmaxf(nx*vx1 + ny*vy1 + nz*vz1, EPS_F);
    const float gv0 = NdotV0 / (NdotV0 * omk + kpe);
    const float gv1 = NdotV1 / (NdotV1 * omk + kpe);
    const float c1v0 = alpha2 * gv0;       // folded into sfac
    const float c1v1 = alpha2 * gv1;
    const float fNV0 = 4.0f * NdotV0;
    const float fNV1 = 4.0f * NdotV1;

    const float f00 = 0.04f + (alb0 - 0.04f) * met;
    const float f01 = 0.04f + (alb1 - 0.04f) * met;
    const float f02 = 0.04f + (alb2 - 0.04f) * met;
    const float omf00 = 1.0f - f00, omf01 = 1.0f - f01, omf02 = 1.0f - f02;
    const float db0 = (1.0f - met) * alb0 * (1.0f / PI_F);
    const float db1 = (1.0f - met) * alb1 * (1.0f / PI_F);
    const float db2 = (1.0f - met) * alb2 * (1.0f / PI_F);

    // ---- vis: 8 samples per lane, two float4 loads ----
    const float* __restrict__ visrow = env_vis + (size_t)n * 512 + lane * 8;
    const float4 vA = *(const float4*)(visrow);
    const float4 vB = *(const float4*)(visrow + 4);
    const float vis[8] = { vA.x, vA.y, vA.z, vA.w, vB.x, vB.y, vB.z, vB.w };

    float a00 = 0.f, a01 = 0.f, a02 = 0.f;   // view 0 rgb
    float a10 = 0.f, a11 = 0.f, a12 = 0.f;   // view 1 rgb

    #pragma unroll
    for (int i = 0; i < 8; ++i) {
        const int idx = i * 64 + lane;        // sigma(lane*8+i)
        const float lx = s_lx[idx];
        const float ly = s_ly[idx];
        const float lz = s_lz[idx];

        const float NdotL = fmaxf(fmaf(nx, lx, fmaf(ny, ly, nz * lz)), EPS_F);
        const float glden = fmaf(NdotL, omk, kpe);
        const float w  = vis[i] * NdotL;
        const float t0 = s_L0[idx] * w;
        const float t1 = s_L1[idx] * w;
        const float t2 = s_L2[idx] * w;

        // ---- view 0 ----
        {
            const float hx = vx0 + lx, hy = vy0 + ly, hz = vz0 + lz;
            const float h2 = fmaf(hx, hx, fmaf(hy, hy, hz * hz));
            const float hinv = __builtin_amdgcn_rsqf(fmaxf(h2, 1e-24f));
            const float nh = fmaf(nx, hx, fmaf(ny, hy, nz * hz));
            const float lh = fmaf(lx, hx, fmaf(ly, hy, lz * hz));
            const float NdotH = fmaxf(nh * hinv, 0.0f);
            const float VdotH = fmaxf(lh * hinv, 0.0f);
            const float p  = 1.0f - fminf(VdotH, 1.0f);
            const float p2 = p * p;
            const float p5 = p2 * p2 * p;
            const float dn   = fmaf(NdotH * NdotH, a2m1, 1.0f);
            const float Dden = fmaf(PI_F * dn, dn, EPS_F);
            const float sden = fmaf(fNV0, NdotL, EPS_F);
            const float sfac = c1v0 * NdotL * __builtin_amdgcn_rcpf(Dden * glden * sden);
            const float sd0 = sfac - db0;
            const float sd1 = sfac - db1;
            const float sd2 = sfac - db2;
            const float Fr0 = fmaf(omf00, p5, f00);
            const float Fr1 = fmaf(omf01, p5, f01);
            const float Fr2 = fmaf(omf02, p5, f02);
            a00 = fmaf(fmaf(Fr0, sd0, db0), t0, a00);
            a01 = fmaf(fmaf(Fr1, sd1, db1), t1, a01);
            a02 = fmaf(fmaf(Fr2, sd2, db2), t2, a02);
        }
        // ---- view 1 ----
        {
            const float hx = vx1 + lx, hy = vy1 + ly, hz = vz1 + lz;
            const float h2 = fmaf(hx, hx, fmaf(hy, hy, hz * hz));
            const float hinv = __builtin_amdgcn_rsqf(fmaxf(h2, 1e-24f));
            const float nh = fmaf(nx, hx, fmaf(ny, hy, nz * hz));
            const float lh = fmaf(lx, hx, fmaf(ly, hy, lz * hz));
            const float NdotH = fmaxf(nh * hinv, 0.0f);
            const float VdotH = fmaxf(lh * hinv, 0.0f);
            const float p  = 1.0f - fminf(VdotH, 1.0f);
            const float p2 = p * p;
            const float p5 = p2 * p2 * p;
            const float dn   = fmaf(NdotH * NdotH, a2m1, 1.0f);
            const float Dden = fmaf(PI_F * dn, dn, EPS_F);
            const float sden = fmaf(fNV1, NdotL, EPS_F);
            const float sfac = c1v1 * NdotL * __builtin_amdgcn_rcpf(Dden * glden * sden);
            const float sd0 = sfac - db0;
            const float sd1 = sfac - db1;
            const float sd2 = sfac - db2;
            const float Fr0 = fmaf(omf00, p5, f00);
            const float Fr1 = fmaf(omf01, p5, f01);
            const float Fr2 = fmaf(omf02, p5, f02);
            a10 = fmaf(fmaf(Fr0, sd0, db0), t0, a10);
            a11 = fmaf(fmaf(Fr1, sd1, db1), t1, a11);
            a12 = fmaf(fmaf(Fr2, sd2, db2), t2, a12);
        }
    }

    // ---- wave64 butterfly reduction (6 accumulators) ----
    #pragma unroll
    for (int off = 32; off >= 1; off >>= 1) {
        a00 += __shfl_down(a00, off, 64);
        a01 += __shfl_down(a01, off, 64);
        a02 += __shfl_down(a02, off, 64);
        a10 += __shfl_down(a10, off, 64);
        a11 += __shfl_down(a11, off, 64);
        a12 += __shfl_down(a12, off, 64);
    }

    if (lane == 0) {
        float* o = out + (size_t)n * 6;
        *(float2*)(o + 0) = make_float2(a00, a01);
        *(float2*)(o + 2) = make_float2(a02, a10);
        *(float2*)(o + 4) = make_float2(a11, a12);
    }
}

extern "C" void kernel_launch(void* const* d_in, const int* in_sizes, int n_in,
                              void* d_out, int out_size, void* d_ws, size_t ws_size,
                              hipStream_t stream) {
    const float* normals  = (const float*)d_in[0];
    const float* albedo   = (const float*)d_in[1];
    const float* metallic = (const float*)d_in[2];
    const float* smooth   = (const float*)d_in[3];
    const float* vdirs    = (const float*)d_in[4];
    const float* env_vis  = (const float*)d_in[5];
    const float* env_map  = (const float*)d_in[6];
    float* out = (float*)d_out;

    const int N = in_sizes[0] / 3;       // 4096 points
    const int blocks = (N + 7) / 8;      // one wave per point, 8 waves/block

    hdr_render_kernel<<<blocks, 512, 0, stream>>>(
        normals, albedo, metallic, smooth, vdirs, env_vis, env_map, out, N);
}